// Round 1
// baseline (145.898 us; speedup 1.0000x reference)
//
#include <hip/hip_runtime.h>

#define B_SZ 8
#define N_SZ 65536
#define C_SZ 128
#define K_SZ 15
#define NT 64
#define THREADS 256
#define INV_KP_EXTENT (1.0f / 0.48f)

// LDS x tile layout (swizzled, float index):
//   addr(n, c) = n*128 + (((c>>2) ^ (n>>2)) << 2) + (c&3)
// write side: 16B unit along c at fixed n; read side: 16B unit along c, bijective per row.

__global__ __launch_bounds__(THREADS) void kpconv_main(
    const float* __restrict__ p, const float* __restrict__ x,
    const float* __restrict__ kp, float* __restrict__ part,
    int tiles_per_block, int blocks_per_b) {
  __shared__ float xt[NT * C_SZ];     // 32 KB
  __shared__ float wt[NT][16];        // 4 KB  (k=15 column zero-padded)
  __shared__ float wf[K_SZ * C_SZ];   // 7.5 KB block accumulator

  const int tid = threadIdx.x;
  const int blk = blockIdx.x;
  const int b  = blk / blocks_per_b;
  const int jb = blk % blocks_per_b;

  for (int i = tid; i < K_SZ * C_SZ; i += THREADS) wf[i] = 0.0f;

  float acc[16][4];
#pragma unroll
  for (int k = 0; k < 16; ++k)
#pragma unroll
    for (int c = 0; c < 4; ++c) acc[k][c] = 0.0f;

  const int c4   = tid & 31;   // compute: c-group (c0 = 4*c4)
  const int nq   = tid >> 5;   // compute: n-octant 0..7
  const int cq   = tid >> 4;   // stage: c-group 0..15 (+16)
  const int npos = tid & 15;   // stage: n-group (4 n's)

  const float* xb = x + (size_t)b * C_SZ * N_SZ;
  const float* pb = p + (size_t)b * N_SZ * 3;

  for (int t = 0; t < tiles_per_block; ++t) {
    const int n0 = (jb * tiles_per_block + t) * NT;
    __syncthreads();  // previous tile fully consumed before overwrite

    // ---- stage x tile: global (n-contiguous) -> reg 4x4 transpose -> LDS (c-contiguous)
#pragma unroll
    for (int u = 0; u < 2; ++u) {
      const int cg = cq + u * 16;                    // 0..31
      const float* src = xb + (size_t)(4 * cg) * N_SZ + n0 + 4 * npos;
      const float4 r0 = *reinterpret_cast<const float4*>(src + 0 * (size_t)N_SZ);
      const float4 r1 = *reinterpret_cast<const float4*>(src + 1 * (size_t)N_SZ);
      const float4 r2 = *reinterpret_cast<const float4*>(src + 2 * (size_t)N_SZ);
      const float4 r3 = *reinterpret_cast<const float4*>(src + 3 * (size_t)N_SZ);
      float* dst = xt + (size_t)(4 * npos) * C_SZ + ((cg ^ npos) << 2);
      *reinterpret_cast<float4*>(dst + 0 * C_SZ) = make_float4(r0.x, r1.x, r2.x, r3.x);
      *reinterpret_cast<float4*>(dst + 1 * C_SZ) = make_float4(r0.y, r1.y, r2.y, r3.y);
      *reinterpret_cast<float4*>(dst + 2 * C_SZ) = make_float4(r0.z, r1.z, r2.z, r3.z);
      *reinterpret_cast<float4*>(dst + 3 * C_SZ) = make_float4(r0.w, r1.w, r2.w, r3.w);
    }

    // ---- kernel-point weights for this tile's 64 n
    for (int i = tid; i < NT * 16; i += THREADS) {
      const int n = i >> 4, k = i & 15;
      float wv = 0.0f;
      if (k < K_SZ) {
        const float px = pb[(size_t)(n0 + n) * 3 + 0];
        const float py = pb[(size_t)(n0 + n) * 3 + 1];
        const float pz = pb[(size_t)(n0 + n) * 3 + 2];
        const float dx = px - kp[k * 3 + 0];
        const float dy = py - kp[k * 3 + 1];
        const float dz = pz - kp[k * 3 + 2];
        const float d = sqrtf(dx * dx + dy * dy + dz * dz);
        wv = fmaxf(1.0f - d * INV_KP_EXTENT, 0.0f);
      }
      wt[n][k] = wv;
    }
    __syncthreads();

    // ---- compute: each thread 4c x 16k over its 8 n
#pragma unroll
    for (int tt = 0; tt < 8; ++tt) {
      const int n = nq * 8 + tt;
      const float4 xv = *reinterpret_cast<const float4*>(
          xt + (size_t)n * C_SZ + ((c4 ^ (n >> 2)) << 2));
      const float4 w0 = *reinterpret_cast<const float4*>(&wt[n][0]);
      const float4 w1 = *reinterpret_cast<const float4*>(&wt[n][4]);
      const float4 w2 = *reinterpret_cast<const float4*>(&wt[n][8]);
      const float4 w3 = *reinterpret_cast<const float4*>(&wt[n][12]);
      const float wk[16] = {w0.x, w0.y, w0.z, w0.w, w1.x, w1.y, w1.z, w1.w,
                            w2.x, w2.y, w2.z, w2.w, w3.x, w3.y, w3.z, w3.w};
      const float xc[4] = {xv.x, xv.y, xv.z, xv.w};
#pragma unroll
      for (int k = 0; k < 16; ++k)
#pragma unroll
        for (int c = 0; c < 4; ++c) acc[k][c] += wk[k] * xc[c];
    }
  }

  // ---- combine the 8 n-octant partials per (k,c) via LDS atomics
  __syncthreads();
#pragma unroll
  for (int k = 0; k < K_SZ; ++k)
#pragma unroll
    for (int c = 0; c < 4; ++c)
      atomicAdd(&wf[k * C_SZ + 4 * c4 + c], acc[k][c]);
  __syncthreads();

  float* pout = part + (size_t)blk * (K_SZ * C_SZ);
  for (int i = tid; i < K_SZ * C_SZ; i += THREADS) pout[i] = wf[i];
}

__global__ __launch_bounds__(C_SZ) void kpconv_reduce_gemm(
    const float* __restrict__ part, const float* __restrict__ W,
    float* __restrict__ out, int blocks_per_b) {
  const int k = blockIdx.x;   // 0..14
  const int b = blockIdx.y;   // 0..7
  const int tid = threadIdx.x;
  __shared__ float row[C_SZ];

  float s = 0.0f;
  const float* pb = part + (size_t)(b * blocks_per_b) * (K_SZ * C_SZ) + k * C_SZ + tid;
  for (int j = 0; j < blocks_per_b; ++j) s += pb[(size_t)j * (K_SZ * C_SZ)];
  row[tid] = s;
  __syncthreads();

  float acc = 0.0f;
  const float* Wk = W + (size_t)k * C_SZ * C_SZ;
#pragma unroll 8
  for (int c = 0; c < C_SZ; ++c) acc += row[c] * Wk[(size_t)c * C_SZ + tid];
  atomicAdd(&out[b * C_SZ + tid], acc);
}

extern "C" void kernel_launch(void* const* d_in, const int* in_sizes, int n_in,
                              void* d_out, int out_size, void* d_ws, size_t ws_size,
                              hipStream_t stream) {
  const float* p  = (const float*)d_in[0];
  const float* x  = (const float*)d_in[1];
  const float* w  = (const float*)d_in[2];
  const float* kp = (const float*)d_in[3];
  float* out  = (float*)d_out;
  float* part = (float*)d_ws;

  int bpb = 64;  // blocks per batch; shrink if workspace is small
  while ((size_t)B_SZ * bpb * K_SZ * C_SZ * sizeof(float) > ws_size && bpb > 1) bpb >>= 1;
  const int tiles_per_block = (N_SZ / NT) / bpb;

  hipMemsetAsync(d_out, 0, (size_t)out_size * sizeof(float), stream);
  kpconv_main<<<dim3(B_SZ * bpb), THREADS, 0, stream>>>(p, x, kp, part,
                                                        tiles_per_block, bpb);
  kpconv_reduce_gemm<<<dim3(K_SZ, B_SZ), C_SZ, 0, stream>>>(part, w, out, bpb);
}

// Round 3
// 133.341 us; speedup vs baseline: 1.0942x; 1.0942x over previous
//
#include <hip/hip_runtime.h>

#define B_SZ 8
#define N_SZ 65536
#define C_SZ 128
#define K_SZ 15
#define THREADS 256
#define NSTEP 32
#define INV_KP_EXTENT (1.0f / 0.48f)

// Each thread owns 4 consecutive c rows (cg = tid>>3) and 4 consecutive n per
// step (ns = tid&7). x streams global->reg->FMA (no LDS staging). Only the
// 15 x 32 per-step weight table lives in LDS, double-buffered, one barrier/step.
// Weight fill: 256 threads cover 15x32 entries as k = tid>>5 and k+8 (p loaded once).

__global__ __launch_bounds__(THREADS) void kpconv_main(
    const float* __restrict__ p, const float* __restrict__ x,
    const float* __restrict__ kp, float* __restrict__ part,
    int steps_per_block, int blocks_per_b) {
  __shared__ float wt[2][K_SZ][NSTEP];
  __shared__ float kps[K_SZ * 3];

  const int tid = threadIdx.x;
  const int blk = blockIdx.x;
  const int b  = blk / blocks_per_b;
  const int jb = blk % blocks_per_b;
  const int nbase = jb * steps_per_block * NSTEP;

  if (tid < K_SZ * 3) kps[tid] = kp[tid];

  const int cg = tid >> 3;  // 0..31  -> c0 = 4*cg
  const int ns = tid & 7;   // 0..7   -> n offset 4*ns within step
  const int wk = tid >> 5;  // weight-compute k: handles wk and wk+8 (0..7)
  const int wn = tid & 31;  // weight-compute n within step

  const float* xb = x + (size_t)b * C_SZ * N_SZ;
  const float* pb = p + (size_t)b * N_SZ * 3;

  float acc[K_SZ][4];
#pragma unroll
  for (int k = 0; k < K_SZ; ++k)
#pragma unroll
    for (int j = 0; j < 4; ++j) acc[k][j] = 0.0f;

  __syncthreads();  // kps visible

  // prologue: weights for step 0 into buf 0 (each thread: k = wk and wk+8)
  {
    const int n = nbase + wn;
    const float px = pb[3 * n + 0], py = pb[3 * n + 1], pz = pb[3 * n + 2];
    {
      const float dx = px - kps[wk * 3 + 0];
      const float dy = py - kps[wk * 3 + 1];
      const float dz = pz - kps[wk * 3 + 2];
      const float d = sqrtf(dx * dx + dy * dy + dz * dz);
      wt[0][wk][wn] = fmaxf(1.0f - d * INV_KP_EXTENT, 0.0f);
    }
    if (wk + 8 < K_SZ) {
      const int k2 = wk + 8;
      const float dx = px - kps[k2 * 3 + 0];
      const float dy = py - kps[k2 * 3 + 1];
      const float dz = pz - kps[k2 * 3 + 2];
      const float d = sqrtf(dx * dx + dy * dy + dz * dz);
      wt[0][k2][wn] = fmaxf(1.0f - d * INV_KP_EXTENT, 0.0f);
    }
  }
  __syncthreads();

  for (int t = 0; t < steps_per_block; ++t) {
    const int n0 = nbase + t * NSTEP;
    const int buf = t & 1;

    // stream x: 4 c-rows x 4 n, coalesced 128B segments per wave-load
    float4 xr[4];
#pragma unroll
    for (int j = 0; j < 4; ++j)
      xr[j] = *reinterpret_cast<const float4*>(
          xb + (size_t)(4 * cg + j) * N_SZ + n0 + 4 * ns);

    // weights for step t+1 into the other buffer (overlaps x-load latency)
    if (t + 1 < steps_per_block) {
      const int n = n0 + NSTEP + wn;
      const float px = pb[3 * n + 0], py = pb[3 * n + 1], pz = pb[3 * n + 2];
      {
        const float dx = px - kps[wk * 3 + 0];
        const float dy = py - kps[wk * 3 + 1];
        const float dz = pz - kps[wk * 3 + 2];
        const float d = sqrtf(dx * dx + dy * dy + dz * dz);
        wt[buf ^ 1][wk][wn] = fmaxf(1.0f - d * INV_KP_EXTENT, 0.0f);
      }
      if (wk + 8 < K_SZ) {
        const int k2 = wk + 8;
        const float dx = px - kps[k2 * 3 + 0];
        const float dy = py - kps[k2 * 3 + 1];
        const float dz = pz - kps[k2 * 3 + 2];
        const float d = sqrtf(dx * dx + dy * dy + dz * dz);
        wt[buf ^ 1][k2][wn] = fmaxf(1.0f - d * INV_KP_EXTENT, 0.0f);
      }
    }

    // FMA: 15 k x 4 c x 4 n = 240 fma/thread/step
#pragma unroll
    for (int k = 0; k < K_SZ; ++k) {
      const float4 wq = *reinterpret_cast<const float4*>(&wt[buf][k][4 * ns]);
#pragma unroll
      for (int j = 0; j < 4; ++j)
        acc[k][j] = fmaf(wq.x, xr[j].x,
                    fmaf(wq.y, xr[j].y,
                    fmaf(wq.z, xr[j].z,
                    fmaf(wq.w, xr[j].w, acc[k][j]))));
    }
    __syncthreads();
  }

  // reduce the 8 n-sublane partials (lanes differing in bits 0..2)
#pragma unroll
  for (int k = 0; k < K_SZ; ++k)
#pragma unroll
    for (int j = 0; j < 4; ++j) {
      float v = acc[k][j];
      v += __shfl_xor(v, 1);
      v += __shfl_xor(v, 2);
      v += __shfl_xor(v, 4);
      acc[k][j] = v;
    }

  if (ns == 0) {
    float* pout = part + (size_t)blk * (K_SZ * C_SZ);
#pragma unroll
    for (int k = 0; k < K_SZ; ++k)
      *reinterpret_cast<float4*>(pout + k * C_SZ + 4 * cg) =
          make_float4(acc[k][0], acc[k][1], acc[k][2], acc[k][3]);
  }
}

__global__ __launch_bounds__(C_SZ) void kpconv_reduce_gemm(
    const float* __restrict__ part, const float* __restrict__ W,
    float* __restrict__ out, int blocks_per_b) {
  const int k = blockIdx.x;   // 0..14
  const int b = blockIdx.y;   // 0..7
  const int tid = threadIdx.x;
  __shared__ float row[C_SZ];

  float s = 0.0f;
  const float* pb = part + (size_t)(b * blocks_per_b) * (K_SZ * C_SZ) + k * C_SZ + tid;
  for (int j = 0; j < blocks_per_b; ++j) s += pb[(size_t)j * (K_SZ * C_SZ)];
  row[tid] = s;
  __syncthreads();

  float acc = 0.0f;
  const float* Wk = W + (size_t)k * C_SZ * C_SZ;
#pragma unroll 8
  for (int c = 0; c < C_SZ; ++c) acc += row[c] * Wk[(size_t)c * C_SZ + tid];
  atomicAdd(&out[b * C_SZ + tid], acc);
}

extern "C" void kernel_launch(void* const* d_in, const int* in_sizes, int n_in,
                              void* d_out, int out_size, void* d_ws, size_t ws_size,
                              hipStream_t stream) {
  const float* p  = (const float*)d_in[0];
  const float* x  = (const float*)d_in[1];
  const float* w  = (const float*)d_in[2];
  const float* kp = (const float*)d_in[3];
  float* out  = (float*)d_out;
  float* part = (float*)d_ws;

  int bpb = 256;  // blocks per batch -> 2048 blocks total
  while ((size_t)B_SZ * bpb * K_SZ * C_SZ * sizeof(float) > ws_size && bpb > 1) bpb >>= 1;
  const int steps_per_block = N_SZ / (bpb * NSTEP);

  hipMemsetAsync(d_out, 0, (size_t)out_size * sizeof(float), stream);
  kpconv_main<<<dim3(B_SZ * bpb), THREADS, 0, stream>>>(p, x, kp, part,
                                                        steps_per_block, bpb);
  kpconv_reduce_gemm<<<dim3(K_SZ, B_SZ), C_SZ, 0, stream>>>(part, w, out, bpb);
}

// Round 4
// 131.694 us; speedup vs baseline: 1.1079x; 1.0125x over previous
//
#include <hip/hip_runtime.h>

#define B_SZ 8
#define N_SZ 65536
#define C_SZ 128
#define K_SZ 15
#define THREADS 256
#define NSTEP 32
#define INV_KP_EXTENT (1.0f / 0.48f)

// Thread (tid): owns 4 consecutive c rows (cg=tid>>3) x 4 n (ns=tid&7) per step.
// x streams global->reg->FMA with a 2-deep register prefetch (xrA/xrB), so step
// t+1's loads are in flight during step t's 240 FMAs. The 15x32 weight table is
// double-buffered in LDS (one barrier per step). Weight fill: k = tid>>5 and k+8.

__global__ __launch_bounds__(THREADS, 4) void kpconv_main(
    const float* __restrict__ p, const float* __restrict__ x,
    const float* __restrict__ kp, float* __restrict__ part,
    int steps_per_block, int blocks_per_b) {
  __shared__ float wt[2][K_SZ][NSTEP];
  __shared__ float kps[K_SZ * 3];

  const int tid = threadIdx.x;
  const int blk = blockIdx.x;
  const int b  = blk / blocks_per_b;
  const int jb = blk % blocks_per_b;
  const int nbase = jb * steps_per_block * NSTEP;

  if (tid < K_SZ * 3) kps[tid] = kp[tid];

  const int cg = tid >> 3;  // 0..31  -> c0 = 4*cg
  const int ns = tid & 7;   // 0..7   -> n offset 4*ns within step
  const int wk = tid >> 5;  // weight-fill k: handles wk and wk+8
  const int wn = tid & 31;  // weight-fill n within step

  const float* xb = x + (size_t)b * C_SZ * N_SZ + nbase + 4 * ns;
  const float* pb = p + (size_t)b * N_SZ * 3;

  float acc[K_SZ][4];
#pragma unroll
  for (int k = 0; k < K_SZ; ++k)
#pragma unroll
    for (int j = 0; j < 4; ++j) acc[k][j] = 0.0f;

#define LOAD_X(dst, toff)                                                     \
  do {                                                                        \
    const float* src_ = xb + (size_t)(toff) * NSTEP;                          \
    _Pragma("unroll")                                                         \
    for (int j_ = 0; j_ < 4; ++j_)                                            \
      dst[j_] = *reinterpret_cast<const float4*>(src_ + (size_t)(4 * cg + j_) * N_SZ); \
  } while (0)

#define FILL_WT(bufi, toff)                                                   \
  do {                                                                        \
    const int n_ = nbase + (toff) * NSTEP + wn;                               \
    const float px_ = pb[3 * n_ + 0], py_ = pb[3 * n_ + 1], pz_ = pb[3 * n_ + 2]; \
    {                                                                         \
      const float dx_ = px_ - kps[wk * 3 + 0];                                \
      const float dy_ = py_ - kps[wk * 3 + 1];                                \
      const float dz_ = pz_ - kps[wk * 3 + 2];                                \
      const float d_ = sqrtf(dx_ * dx_ + dy_ * dy_ + dz_ * dz_);              \
      wt[bufi][wk][wn] = fmaxf(1.0f - d_ * INV_KP_EXTENT, 0.0f);              \
    }                                                                         \
    if (wk + 8 < K_SZ) {                                                      \
      const int k2_ = wk + 8;                                                 \
      const float dx_ = px_ - kps[k2_ * 3 + 0];                               \
      const float dy_ = py_ - kps[k2_ * 3 + 1];                               \
      const float dz_ = pz_ - kps[k2_ * 3 + 2];                               \
      const float d_ = sqrtf(dx_ * dx_ + dy_ * dy_ + dz_ * dz_);              \
      wt[bufi][k2_][wn] = fmaxf(1.0f - d_ * INV_KP_EXTENT, 0.0f);             \
    }                                                                         \
  } while (0)

#define DO_FMA(xr, bufi)                                                      \
  do {                                                                        \
    _Pragma("unroll")                                                         \
    for (int k_ = 0; k_ < K_SZ; ++k_) {                                       \
      const float4 wq_ = *reinterpret_cast<const float4*>(&wt[bufi][k_][4 * ns]); \
      _Pragma("unroll")                                                       \
      for (int j_ = 0; j_ < 4; ++j_)                                          \
        acc[k_][j_] = fmaf(wq_.x, xr[j_].x,                                   \
                      fmaf(wq_.y, xr[j_].y,                                   \
                      fmaf(wq_.z, xr[j_].z,                                   \
                      fmaf(wq_.w, xr[j_].w, acc[k_][j_]))));                  \
    }                                                                         \
  } while (0)

  float4 xrA[4], xrB[4];
  __syncthreads();        // kps visible
  FILL_WT(0, 0);          // weights step 0
  LOAD_X(xrA, 0);         // x step 0
  __syncthreads();        // wt[0] visible

  for (int t = 0; t < steps_per_block; t += 2) {
    // even step t: consume xrA / wt[0]; prefetch t+1 into xrB / wt[1]
    if (t + 1 < steps_per_block) {
      LOAD_X(xrB, t + 1);
      FILL_WT(1, t + 1);
    }
    DO_FMA(xrA, 0);
    __syncthreads();
    // odd step t+1: consume xrB / wt[1]; prefetch t+2 into xrA / wt[0]
    if (t + 1 < steps_per_block) {
      if (t + 2 < steps_per_block) {
        LOAD_X(xrA, t + 2);
        FILL_WT(0, t + 2);
      }
      DO_FMA(xrB, 1);
      __syncthreads();
    }
  }

  // reduce the 8 n-sublane partials (lanes differing in bits 0..2)
#pragma unroll
  for (int k = 0; k < K_SZ; ++k)
#pragma unroll
    for (int j = 0; j < 4; ++j) {
      float v = acc[k][j];
      v += __shfl_xor(v, 1);
      v += __shfl_xor(v, 2);
      v += __shfl_xor(v, 4);
      acc[k][j] = v;
    }

  if (ns == 0) {
    float* pout = part + (size_t)blk * (K_SZ * C_SZ);
#pragma unroll
    for (int k = 0; k < K_SZ; ++k)
      *reinterpret_cast<float4*>(pout + k * C_SZ + 4 * cg) =
          make_float4(acc[k][0], acc[k][1], acc[k][2], acc[k][3]);
  }
}

__global__ __launch_bounds__(C_SZ) void kpconv_reduce_gemm(
    const float* __restrict__ part, const float* __restrict__ W,
    float* __restrict__ out, int blocks_per_b) {
  const int k = blockIdx.x;   // 0..14
  const int b = blockIdx.y;   // 0..7
  const int tid = threadIdx.x;
  __shared__ float row[C_SZ];

  float s = 0.0f;
  const float* pb = part + (size_t)(b * blocks_per_b) * (K_SZ * C_SZ) + k * C_SZ + tid;
  for (int j = 0; j < blocks_per_b; ++j) s += pb[(size_t)j * (K_SZ * C_SZ)];
  row[tid] = s;
  __syncthreads();

  float acc = 0.0f;
  const float* Wk = W + (size_t)k * C_SZ * C_SZ;
#pragma unroll 8
  for (int c = 0; c < C_SZ; ++c) acc += row[c] * Wk[(size_t)c * C_SZ + tid];
  atomicAdd(&out[b * C_SZ + tid], acc);
}

extern "C" void kernel_launch(void* const* d_in, const int* in_sizes, int n_in,
                              void* d_out, int out_size, void* d_ws, size_t ws_size,
                              hipStream_t stream) {
  const float* p  = (const float*)d_in[0];
  const float* x  = (const float*)d_in[1];
  const float* w  = (const float*)d_in[2];
  const float* kp = (const float*)d_in[3];
  float* out  = (float*)d_out;
  float* part = (float*)d_ws;

  int bpb = 256;  // blocks per batch -> 2048 blocks total, 8 steps each
  while ((size_t)B_SZ * bpb * K_SZ * C_SZ * sizeof(float) > ws_size && bpb > 1) bpb >>= 1;
  const int steps_per_block = N_SZ / (bpb * NSTEP);

  hipMemsetAsync(d_out, 0, (size_t)out_size * sizeof(float), stream);
  kpconv_main<<<dim3(B_SZ * bpb), THREADS, 0, stream>>>(p, x, kp, part,
                                                        steps_per_block, bpb);
  kpconv_reduce_gemm<<<dim3(K_SZ, B_SZ), C_SZ, 0, stream>>>(part, w, out, bpb);
}